// Round 10
// baseline (296.045 us; speedup 1.0000x reference)
//
#include <hip/hip_runtime.h>
#include <hip/hip_bf16.h>
#include <stdint.h>

#define IN_F 1024
#define OUT_F 1024
#define NB 8
#define KDIM (IN_F + IN_F * NB)  /* 9216 */
#define NROWS 4096
#define SLICE_ELEMS (NROWS * OUT_F)
#define PREP_BLOCKS ((NROWS * IN_F) / 256)        /* 16384 */
#define WCONV_BLOCKS ((OUT_F * KDIM) / (4 * 256)) /* 9216  */

typedef __attribute__((ext_vector_type(8))) short bf16x8;
typedef __attribute__((ext_vector_type(4))) short bf16x4;
typedef __attribute__((ext_vector_type(4))) float f32x4;

// Closed-form uniform cubic B-spline (knots t_j = -2.2 + 0.4j; EPS=1e-8 shift is
// far below bf16 rounding). For x in [t_i,t_{i+1}): 4 nonzero cardinal cubics.
__device__ __forceinline__ void bspline8(float x, float b8[8]) {
  float u = (x + 2.2f) * 2.5f;  // (x - t0)/h
  bool in = (u >= 0.0f) && (u < 11.0f);
  float uc = fminf(fmaxf(u, 0.0f), 10.99f);
  int i = (int)uc;
  float f = uc - (float)i;
  float g = 1.0f - f;
  float f2 = f * f, f3 = f2 * f;
  const float s = 1.0f / 6.0f;
  float v0 = f3 * s;
  float v1 = (-3.0f * f3 + 3.0f * f2 + 3.0f * f + 1.0f) * s;
  float v2 = (3.0f * f3 - 6.0f * f2 + 4.0f) * s;
  float v3 = g * g * g * s;
#pragma unroll
  for (int j = 0; j < 8; ++j) {
    int d = i - j;
    float r = (d == 0) ? v0 : (d == 1) ? v1 : (d == 2) ? v2 : (d == 3) ? v3 : 0.0f;
    b8[j] = in ? r : 0.0f;
  }
}

// Fused prep (A build) + weight conversion, branch on blockIdx (block-uniform).
__global__ void prep_all_kernel(const float* __restrict__ x, const float* __restrict__ bw,
                                const float* __restrict__ sw, __hip_bfloat16* __restrict__ A,
                                __hip_bfloat16* __restrict__ W) {
  if (blockIdx.x < PREP_BLOCKS) {
    int idx = blockIdx.x * 256 + threadIdx.x;
    int n = idx >> 10;
    int i = idx & 1023;
    float xv = x[idx];
    float sl = xv / (1.0f + __expf(-xv));
    __hip_bfloat16* row = A + (size_t)n * KDIM;
    row[i] = __float2bfloat16(sl);
    float b8[8];
    bspline8(xv, b8);
    alignas(16) __hip_bfloat16 tmp[8];
#pragma unroll
    for (int c = 0; c < 8; ++c) tmp[c] = __float2bfloat16(b8[c]);
    *(bf16x8*)(row + IN_F + i * 8) = *(const bf16x8*)tmp;
  } else {
    int v = (blockIdx.x - PREP_BLOCKS) * 256 + threadIdx.x;
    int e = v * 4;
    int o = e / KDIM;
    int k = e - o * KDIM;
    float4 val = (k < IN_F) ? *(const float4*)(bw + o * IN_F + k)
                            : *(const float4*)(sw + (size_t)o * (IN_F * NB) + (k - IN_F));
    alignas(8) __hip_bfloat16 t[4];
    t[0] = __float2bfloat16(val.x);
    t[1] = __float2bfloat16(val.y);
    t[2] = __float2bfloat16(val.z);
    t[3] = __float2bfloat16(val.w);
    *(bf16x4*)(W + e) = *(const bf16x4*)t;
  }
}

// ---------------------------------------------------------------------------
// R10: OCCUPANCY, not schedule. R2/R3/R6/R7/R9 (six schedules, 512thr,
// >=64KB LDS -> 1 block/CU = 2 waves/SIMD) all plateau at 100-122us /
// MfmaUtil ~30%: both waves of a SIMD sit at the SAME barrier, so every
// drain is exposed (measured 3433 cyc/tile vs 1242 MFMA floor; LDS pipe
// only ~150 cyc at 85B/cyc -- never the bottleneck). m97/m114 evidence:
// the 128-tile structure hits 874-912 TF at ~3 blocks/CU purely from
// cross-block overlap (one block's MFMA covers another's barrier drain).
// So: 128x128 tile, 256 thr (4 waves), BK=32, dbuf LDS = 32 KB -> 4-5
// blocks/CU by LDS; simple one-syncthreads-per-tile m97 schedule.
// LDS fragment-ordered (512-elem groups of 16 rows x 32k; lane l: row=l&15,
// kchunk=l>>4) -> ds/stage addrs = uniform base + 16B*lane: conflict-free,
// legal for global_load_lds. Grid 32x8x4 = 1024 blocks = 4/CU.
// ---------------------------------------------------------------------------
__global__ __launch_bounds__(256) void gemm11_kernel(const __hip_bfloat16* __restrict__ A,
                                                     const __hip_bfloat16* __restrict__ W,
                                                     float* __restrict__ dst,
                                                     const float* __restrict__ bias,
                                                     int kslice, int use_bias) {
  __shared__ __hip_bfloat16 lA[2][4096];
  __shared__ __hip_bfloat16 lB[2][4096];
  const int tid = threadIdx.x;
  const int wave = tid >> 6;
  const int lane = tid & 63;
  const int bm = blockIdx.x * 128;
  const int bn = blockIdx.y * 128;
  const int z = blockIdx.z;
  float* __restrict__ d = dst + (size_t)z * SLICE_ELEMS;
  const int kbeg = z * kslice;
  const int NT = kslice >> 5;  // K-tiles of 32 (72 at S=4)
  const int srow = lane & 15;
  const int skc = (lane >> 4) * 8;
  const int wm = (wave & 1) * 64;
  const int wn = (wave >> 1) * 64;
  const int r = lane & 15;
  const int quad = lane >> 4;

  // wave stages 16-row groups 2w, 2w+1 of A and B (1 gload each: 64 lanes x 16B
  // = 1 KB = one 512-elem group).
  const int g0 = wave * 2;
  const __hip_bfloat16* gA[2];
  const __hip_bfloat16* gB[2];
  gA[0] = A + (size_t)(bm + g0 * 16 + srow) * KDIM + kbeg + skc;
  gA[1] = gA[0] + (size_t)16 * KDIM;
  gB[0] = W + (size_t)(bn + g0 * 16 + srow) * KDIM + kbeg + skc;
  gB[1] = gB[0] + (size_t)16 * KDIM;

  f32x4 acc[4][4];
#pragma unroll
  for (int a = 0; a < 4; ++a)
#pragma unroll
    for (int b = 0; b < 4; ++b) acc[a][b] = (f32x4){0.f, 0.f, 0.f, 0.f};

#define GLOAD(SRC, DST)                                                                      \
  __builtin_amdgcn_global_load_lds((const __attribute__((address_space(1))) void*)(SRC),     \
                                   (__attribute__((address_space(3))) void*)(DST), 16, 0, 0)

#define STAGE(IT, BUF)                                               \
  do {                                                               \
    const size_t koff_ = (size_t)(IT) * 32;                          \
    _Pragma("unroll") for (int h = 0; h < 2; ++h) {                  \
      GLOAD(gA[h] + koff_, &lA[BUF][(g0 + h) * 512]);                \
      GLOAD(gB[h] + koff_, &lB[BUF][(g0 + h) * 512]);                \
    }                                                                \
  } while (0)

  STAGE(0, 0);
  __syncthreads();

  for (int it = 0; it < NT; ++it) {
    const int p = it & 1;
    if (it + 1 < NT) STAGE(it + 1, p ^ 1);  // in flight across compute phase

    bf16x8 af[4], bfr[4];
#pragma unroll
    for (int t = 0; t < 4; ++t) {
      af[t] = *(const bf16x8*)&lA[p][((wm >> 4) + t) * 512 + lane * 8];
      bfr[t] = *(const bf16x8*)&lB[p][((wn >> 4) + t) * 512 + lane * 8];
    }
#pragma unroll
    for (int tm = 0; tm < 4; ++tm)
#pragma unroll
      for (int tn = 0; tn < 4; ++tn)
        acc[tm][tn] =
            __builtin_amdgcn_mfma_f32_16x16x32_bf16(af[tm], bfr[tn], acc[tm][tn], 0, 0, 0);

    __syncthreads();  // drains vmcnt (tile it+1 staged) + all waves done with buf p
  }
#undef STAGE
#undef GLOAD

  // C/D map: col=lane&15, row=quad*4+reg (m89-verified).
#pragma unroll
  for (int tm = 0; tm < 4; ++tm) {
#pragma unroll
    for (int tn = 0; tn < 4; ++tn) {
      const int col = bn + wn + tn * 16 + r;
      const float bv = use_bias ? bias[col] : 0.0f;
#pragma unroll
      for (int reg = 0; reg < 4; ++reg) {
        const int rowi = bm + wm + tm * 16 + quad * 4 + reg;
        d[(size_t)rowi * OUT_F + col] = acc[tm][tn][reg] + bv;
      }
    }
  }
}

// out = bias + sum_s partial[s], float4 per thread.
__global__ void reduce_kernel(const float* __restrict__ P, const float* __restrict__ bias,
                              float* __restrict__ out, int S) {
  int v = blockIdx.x * 256 + threadIdx.x;
  int e = v * 4;
  int o = e & (OUT_F - 1);
  float4 acc = *(const float4*)(bias + o);
  for (int s = 0; s < S; ++s) {
    float4 p = *(const float4*)(P + (size_t)s * SLICE_ELEMS + e);
    acc.x += p.x;
    acc.y += p.y;
    acc.z += p.z;
    acc.w += p.w;
  }
  *(float4*)(out + e) = acc;
}

// Emergency fallback if ws is too small for A+W (fp32, slow but correct).
__global__ void kan_fallback(const float* __restrict__ x, const float* __restrict__ bw,
                             const float* __restrict__ bb, const float* __restrict__ sw,
                             float* __restrict__ out) {
  __shared__ float act[KDIM];
  int n = blockIdx.x;
  for (int i = threadIdx.x; i < IN_F; i += 256) {
    float xv = x[(size_t)n * IN_F + i];
    act[i] = xv / (1.0f + __expf(-xv));
    float b8[8];
    bspline8(xv, b8);
#pragma unroll
    for (int c = 0; c < 8; ++c) act[IN_F + i * 8 + c] = b8[c];
  }
  __syncthreads();
  for (int o = threadIdx.x; o < OUT_F; o += 256) {
    float s = bb[o];
    const float* wbp = bw + (size_t)o * IN_F;
    for (int k = 0; k < IN_F; ++k) s += act[k] * wbp[k];
    const float* wsp = sw + (size_t)o * (IN_F * NB);
    for (int k = 0; k < IN_F * NB; ++k) s += act[IN_F + k] * wsp[k];
    out[(size_t)n * OUT_F + o] = s;
  }
}

extern "C" void kernel_launch(void* const* d_in, const int* in_sizes, int n_in, void* d_out,
                              int out_size, void* d_ws, size_t ws_size, hipStream_t stream) {
  const float* x = (const float*)d_in[0];
  const float* bw = (const float*)d_in[1];
  const float* bb = (const float*)d_in[2];
  const float* sw = (const float*)d_in[3];
  float* out = (float*)d_out;

  const size_t needA = (size_t)NROWS * KDIM * 2;  // 75.5 MB
  const size_t needW = (size_t)OUT_F * KDIM * 2;  // 18.9 MB
  const size_t sliceB = (size_t)SLICE_ELEMS * 4;  // 16.8 MB
  if (ws_size < needA + needW) {
    kan_fallback<<<NROWS, 256, 0, stream>>>(x, bw, bb, sw, out);
    return;
  }
  __hip_bfloat16* A = (__hip_bfloat16*)d_ws;
  __hip_bfloat16* W = (__hip_bfloat16*)((char*)d_ws + needA);
  float* P = (float*)((char*)d_ws + needA + needW);
  const size_t avail = ws_size - needA - needW;
  // S=4 -> 32x8x4 = 1024 blocks; 32 KB LDS -> 4 blocks/CU co-resident.
  int S = (avail >= 4 * sliceB) ? 4 : (avail >= 2 * sliceB) ? 2 : 1;

  prep_all_kernel<<<PREP_BLOCKS + WCONV_BLOCKS, 256, 0, stream>>>(x, bw, sw, A, W);
  if (S == 1) {
    gemm11_kernel<<<dim3(NROWS / 128, OUT_F / 128, 1), 256, 0, stream>>>(A, W, out, bb, KDIM, 1);
  } else {
    gemm11_kernel<<<dim3(NROWS / 128, OUT_F / 128, S), 256, 0, stream>>>(A, W, P, bb, KDIM / S, 0);
    reduce_kernel<<<SLICE_ELEMS / (4 * 256), 256, 0, stream>>>(P, bb, out, S);
  }
}